// Round 2
// baseline (14435.866 us; speedup 1.0000x reference)
//
#include <hip/hip_runtime.h>
#include <hip/hip_bf16.h>

typedef unsigned short ushort_t;
typedef unsigned int uint_t;
using f32x4 = __attribute__((ext_vector_type(4))) float;
using short8 = __attribute__((ext_vector_type(8))) short;

#define MFMA_B16(a,b,c) __builtin_amdgcn_mfma_f32_16x16x32_bf16((a),(b),(c),0,0,0)

static __device__ __forceinline__ float bf2f(ushort_t u){
  unsigned v = ((unsigned)u) << 16;
  return __builtin_bit_cast(float, v);
}
static __device__ __forceinline__ ushort_t f2bf(float f){
  __hip_bfloat16 h = __float2bfloat16(f);
  return __builtin_bit_cast(unsigned short, h);
}

// ws layout (bf16 elements unless noted):
//   [0, 524288)      : weights, 2048 rows x 256 k (row-major)
//       rows    0- 767 : xproj B  (Wzx^T 0-255, Wrx^T 256-511, Wtx^T 512-767)
//       rows  768-1023 : Wzh^T ; 1024-1279 : Wrh^T ; 1280-1535 : Wth^T ; 1536-2047 : Wd^T
//   [524288, 542208) : aux  (bz 0-255 | br 256-511 | btx 512-767 | bth 768-1023 |
//                            bd 1024-1535 | h0 1536-17919)
//   byte 1084416     : uint flag (1 = inputs are bf16, 0 = f32)
//   byte 2097152+    : Ax (65536 x 768, f32 or bf16 per ws_size)
#define W_ELEMS  524288
#define AUX_OFF  524288
#define AUX_BTH  768
#define AUX_BD   1024
#define AUX_H0   1536
#define AUX_ELEMS 17920
#define FLAG_BYTE 1084416u
#define AX_OFF_BYTES (2u<<20)
#define ROW_ZH 768
#define ROW_RH 1024
#define ROW_TH 1280
#define ROW_D  1536

// ---------------------------------------------------------------- dtype detect
// bf16-pair words have bits14:7 (low element's exponent) in [100,136] ~always;
// f32 words have uniform mantissa bits there (~14% hit rate).
__global__ __launch_bounds__(64) void detect_kernel(const uint_t* __restrict__ x,
                                                    uint_t* __restrict__ flag)
{
  int l = threadIdx.x;
  int cnt = 0;
  for (int i = 0; i < 8; ++i){
    uint_t w = x[i*64 + l];
    uint_t e = (w >> 7) & 0xFF;
    unsigned long long m = __ballot(e >= 100 && e <= 136);
    if (l == 0) cnt += __popcll(m);
  }
  if (l == 0) *flag = (cnt >= 256) ? 1u : 0u;
}

// ---------------------------------------------------------------- prep (canonicalize to bf16)
__global__ __launch_bounds__(256) void prep_kernel(
    const void* __restrict__ Wz, const void* __restrict__ Wr,
    const void* __restrict__ Wtx, const void* __restrict__ Wth,
    const void* __restrict__ Wd,
    const void* __restrict__ bz, const void* __restrict__ br,
    const void* __restrict__ btx, const void* __restrict__ bth,
    const void* __restrict__ bd, const void* __restrict__ h0,
    const uint_t* __restrict__ flag, ushort_t* __restrict__ o)
{
  const bool b16 = (*flag != 0);
  int i = blockIdx.x * 256 + threadIdx.x;          // < 542208
  const void* src; int idx;
  if (i < W_ELEMS){
    int row = i >> 8, k = i & 255;
    if      (row <  256){ src = Wz;  idx = k*256 + row;         }
    else if (row <  512){ src = Wr;  idx = k*256 + (row-256);   }
    else if (row <  768){ src = Wtx; idx = k*256 + (row-512);   }
    else if (row < 1024){ src = Wz;  idx = (256+k)*256 + (row-768);  }
    else if (row < 1280){ src = Wr;  idx = (256+k)*256 + (row-1024); }
    else if (row < 1536){ src = Wth; idx = k*256 + (row-1280);  }
    else                { src = Wd;  idx = k*512 + (row-1536);  }
  } else {
    int j = i - W_ELEMS;
    if      (j <  256){ src = bz;  idx = j;       }
    else if (j <  512){ src = br;  idx = j-256;   }
    else if (j <  768){ src = btx; idx = j-512;   }
    else if (j < 1024){ src = bth; idx = j-768;   }
    else if (j < 1536){ src = bd;  idx = j-1024;  }
    else              { src = h0;  idx = j-1536;  }
  }
  o[i] = b16 ? ((const ushort_t*)src)[idx] : f2bf(((const float*)src)[idx]);
}

// ---------------------------------------------------------------- x projection GEMM
// Ax[m][c], m = b*1024 + t (65536 rows), c in [0,768)
template<typename OutT>
__global__ __launch_bounds__(256) void xproj_kernel(
    const void* __restrict__ x, const ushort_t* __restrict__ wsB,
    const ushort_t* __restrict__ aux, const uint_t* __restrict__ flag,
    OutT* __restrict__ Ax)
{
  __shared__ ushort_t As[32768];               // 128 rows x 256 k, swizzled, 64 KB
  const bool b16 = (*flag != 0);
  const int tid = threadIdx.x, w = tid >> 6, l = tid & 63, lr = l & 15, lg = l >> 4;
  const int mt = blockIdx.x % 512, nb = blockIdx.x / 512;
  const int m0 = mt * 128, n0 = nb * 128;

  // stage A tile (reg-staged, XOR granule swizzle), convert to bf16 if needed
  #pragma unroll
  for (int i = 0; i < 16; ++i){
    int gidx = i*256 + tid, row = gidx >> 5, g = gidx & 31;
    short8 v;
    if (b16){
      v = *reinterpret_cast<const short8*>((const ushort_t*)x + (m0+row)*256 + g*8);
    } else {
      const f32x4* xf = reinterpret_cast<const f32x4*>((const float*)x + (m0+row)*256 + g*8);
      f32x4 a0 = xf[0], a1 = xf[1];
      v[0]=(short)f2bf(a0[0]); v[1]=(short)f2bf(a0[1]); v[2]=(short)f2bf(a0[2]); v[3]=(short)f2bf(a0[3]);
      v[4]=(short)f2bf(a1[0]); v[5]=(short)f2bf(a1[1]); v[6]=(short)f2bf(a1[2]); v[7]=(short)f2bf(a1[3]);
    }
    *reinterpret_cast<short8*>(reinterpret_cast<char*>(As) + row*512 + ((g ^ (row&7)) << 4)) = v;
  }
  __syncthreads();

  const int wr = w >> 1, wc = w & 1;
  f32x4 acc[4][4];
  #pragma unroll
  for (int a = 0; a < 4; ++a)
    #pragma unroll
    for (int b = 0; b < 4; ++b) acc[a][b] = (f32x4){0.f,0.f,0.f,0.f};

  #pragma unroll
  for (int ks = 0; ks < 8; ++ks){
    short8 av[4], bv[4];
    #pragma unroll
    for (int mi = 0; mi < 4; ++mi){
      int rT = 64*wr + 16*mi + lr, g = ks*4 + lg;
      av[mi] = *reinterpret_cast<const short8*>(reinterpret_cast<const char*>(As) + rT*512 + ((g ^ (rT&7)) << 4));
    }
    #pragma unroll
    for (int ni = 0; ni < 4; ++ni){
      int nr = n0 + 64*wc + 16*ni + lr;
      bv[ni] = *reinterpret_cast<const short8*>(wsB + nr*256 + ks*32 + lg*8);
    }
    #pragma unroll
    for (int mi = 0; mi < 4; ++mi)
      #pragma unroll
      for (int ni = 0; ni < 4; ++ni)
        acc[mi][ni] = MFMA_B16(av[mi], bv[ni], acc[mi][ni]);
  }

  #pragma unroll
  for (int ni = 0; ni < 4; ++ni){
    int c = n0 + 64*wc + 16*ni + lr;             // [0,768): bz|br|btx consecutive in aux
    float bias = bf2f(aux[c]);
    #pragma unroll
    for (int mi = 0; mi < 4; ++mi)
      #pragma unroll
      for (int j = 0; j < 4; ++j){
        int m = m0 + 64*wr + 16*mi + lg*4 + j;
        float v = acc[mi][ni][j] + bias;
        if constexpr (sizeof(OutT) == 4) Ax[m*768 + c] = v;
        else                             Ax[m*768 + c] = f2bf(v);
      }
  }
}

// ---------------------------------------------------------------- recurrent kernel
// 4 WGs x 512 threads; WG owns 16 batch rows. 8 waves; wave w owns cols [32w,32w+32).
// LDS: [0,131072) Wth^T swizzled | [131072,+8192) h bf16 | [139264,+8192) h_base bf16
template<typename AxT>
__global__ __launch_bounds__(512) void gru_kernel(
    const ushort_t* __restrict__ ws16, const AxT* __restrict__ Ax,
    const void* __restrict__ eps, const uint_t* __restrict__ flag,
    void* __restrict__ outp)
{
  extern __shared__ char smem[];
  const bool b16 = (*flag != 0);
  const ushort_t* e16 = (const ushort_t*)eps;
  const float*    e32 = (const float*)eps;
  ushort_t* o16 = (ushort_t*)outp;
  float*    o32 = (float*)outp;
  const ushort_t* aux = ws16 + AUX_OFF;
  const int tid = threadIdx.x, w = tid >> 6, l = tid & 63, lr = l & 15, lg = l >> 4;
  const int b0 = blockIdx.x * 16;
  const int c0 = 32 * w;

  // stage Wth^T into LDS (swizzled)
  for (int gi = tid; gi < 8192; gi += 512){
    int row = gi >> 5, g = gi & 31;
    short8 v = *reinterpret_cast<const short8*>(ws16 + (ROW_TH + row)*256 + g*8);
    *reinterpret_cast<short8*>(smem + row*512 + ((g ^ (row&7)) << 4)) = v;
  }

  // VGPR-resident B fragments for Wzh, Wrh
  short8 wzh[2][8], wrh[2][8];
  #pragma unroll
  for (int nt = 0; nt < 2; ++nt)
    #pragma unroll
    for (int ks = 0; ks < 8; ++ks){
      wzh[nt][ks] = *reinterpret_cast<const short8*>(ws16 + (ROW_ZH + c0 + 16*nt + lr)*256 + ks*32 + lg*8);
      wrh[nt][ks] = *reinterpret_cast<const short8*>(ws16 + (ROW_RH + c0 + 16*nt + lr)*256 + ks*32 + lg*8);
    }

  float bthv[2], bdm[2], bdl[2];
  #pragma unroll
  for (int nt = 0; nt < 2; ++nt){
    int c = c0 + 16*nt + lr;
    bthv[nt] = bf2f(aux[AUX_BTH + c]);
    bdm[nt]  = bf2f(aux[AUX_BD + c]);
    bdl[nt]  = bf2f(aux[AUX_BD + 256 + c]);
  }

  // h carried in fp32 regs; lane layout == MFMA C layout (row=lg*4+j, col=c0+16nt+lr)
  float hreg[2][4];
  #pragma unroll
  for (int nt = 0; nt < 2; ++nt)
    #pragma unroll
    for (int j = 0; j < 4; ++j){
      int row = lg*4 + j, c = c0 + 16*nt + lr;
      float hv = bf2f(aux[AUX_H0 + (b0+row)*256 + c]);
      hreg[nt][j] = hv;
      *reinterpret_cast<ushort_t*>(smem + 131072 + row*512 + (((c>>3) ^ (row&7)) << 4) + (c&7)*2) = f2bf(hv);
    }
  __syncthreads();

  const ushort_t* wdB = ws16 + ROW_D*256;
  int prow[4];
  prow[0] = 32*w + lr;           // mean n-tile 0
  prow[1] = 32*w + 16 + lr;      // mean n-tile 1
  prow[2] = 256 + 32*w + lr;     // logvar n-tile 0
  prow[3] = 256 + 32*w + 16 + lr;// logvar n-tile 1

  for (int t = 0; t < 1024; ++t){
    // this step's global reads (Ax, eps)
    float axz[2][4], axr[2][4], axt[2][4], epsv[2][4];
    #pragma unroll
    for (int nt = 0; nt < 2; ++nt)
      #pragma unroll
      for (int j = 0; j < 4; ++j){
        int bb = b0 + lg*4 + j, c = c0 + 16*nt + lr;
        int mrow = bb*1024 + t;
        const AxT* ap = Ax + mrow*768 + c;
        if constexpr (sizeof(AxT) == 4){
          axz[nt][j] = ap[0]; axr[nt][j] = ap[256]; axt[nt][j] = ap[512];
        } else {
          axz[nt][j] = bf2f(ap[0]); axr[nt][j] = bf2f(ap[256]); axt[nt][j] = bf2f(ap[512]);
        }
        int ei = mrow*256 + c;
        epsv[nt][j] = b16 ? bf2f(e16[ei]) : e32[ei];
      }

    // ---- phase 1: z,r,(h@Wth+bth) over this wave's 32 cols
    f32x4 az[2], ar[2], at[2];
    #pragma unroll
    for (int nt = 0; nt < 2; ++nt){
      az[nt] = (f32x4){0.f,0.f,0.f,0.f};
      ar[nt] = (f32x4){0.f,0.f,0.f,0.f};
      at[nt] = (f32x4){bthv[nt],bthv[nt],bthv[nt],bthv[nt]};
    }
    #pragma unroll
    for (int ks = 0; ks < 8; ++ks){
      int g = ks*4 + lg;
      short8 a = *reinterpret_cast<const short8*>(smem + 131072 + lr*512 + ((g ^ (lr&7)) << 4));
      int nc0 = c0 + lr, nc1 = c0 + 16 + lr;
      short8 th0 = *reinterpret_cast<const short8*>(smem + nc0*512 + ((g ^ (nc0&7)) << 4));
      short8 th1 = *reinterpret_cast<const short8*>(smem + nc1*512 + ((g ^ (nc1&7)) << 4));
      az[0] = MFMA_B16(a, wzh[0][ks], az[0]);  az[1] = MFMA_B16(a, wzh[1][ks], az[1]);
      ar[0] = MFMA_B16(a, wrh[0][ks], ar[0]);  ar[1] = MFMA_B16(a, wrh[1][ks], ar[1]);
      at[0] = MFMA_B16(a, th0, at[0]);         at[1] = MFMA_B16(a, th1, at[1]);
    }

    // prefetch Wd k-steps 0,1
    short8 wdq[4][2];
    #pragma unroll
    for (int p = 0; p < 4; ++p)
      #pragma unroll
      for (int kk = 0; kk < 2; ++kk)
        wdq[p][kk] = *reinterpret_cast<const short8*>(wdB + prow[p]*256 + kk*32 + lg*8);

    // activations -> h_base (bf16 into LDS)
    #pragma unroll
    for (int nt = 0; nt < 2; ++nt)
      #pragma unroll
      for (int j = 0; j < 4; ++j){
        float zp = az[nt][j] + axz[nt][j];
        float rp = ar[nt][j] + axr[nt][j];
        float zv = 1.f/(1.f + __expf(-zp));
        float rv = 1.f/(1.f + __expf(-rp));
        float tp = axt[nt][j] + rv*at[nt][j];
        float e2 = __expf(-2.f*fabsf(tp));
        float tv = (1.f - e2)/(1.f + e2);
        tv = (tp < 0.f) ? -tv : tv;
        float hb = zv*hreg[nt][j] + (1.f - zv)*tv;
        int row = lg*4 + j, c = c0 + 16*nt + lr;
        *reinterpret_cast<ushort_t*>(smem + 139264 + row*512 + (((c>>3) ^ (row&7)) << 4) + (c&7)*2) = f2bf(hb);
      }
    __syncthreads();

    // ---- phase 2: params = h_base @ Wd + bd (Wd streamed, 2-deep pipeline)
    f32x4 ap4[4];
    ap4[0] = (f32x4){bdm[0],bdm[0],bdm[0],bdm[0]};
    ap4[1] = (f32x4){bdm[1],bdm[1],bdm[1],bdm[1]};
    ap4[2] = (f32x4){bdl[0],bdl[0],bdl[0],bdl[0]};
    ap4[3] = (f32x4){bdl[1],bdl[1],bdl[1],bdl[1]};
    #pragma unroll
    for (int ks = 0; ks < 8; ++ks){
      int g = ks*4 + lg;
      short8 a = *reinterpret_cast<const short8*>(smem + 139264 + lr*512 + ((g ^ (lr&7)) << 4));
      short8 w0 = wdq[0][ks&1], w1 = wdq[1][ks&1], w2 = wdq[2][ks&1], w3 = wdq[3][ks&1];
      if (ks < 6){
        #pragma unroll
        for (int p = 0; p < 4; ++p)
          wdq[p][ks&1] = *reinterpret_cast<const short8*>(wdB + prow[p]*256 + (ks+2)*32 + lg*8);
      }
      ap4[0] = MFMA_B16(a, w0, ap4[0]);
      ap4[1] = MFMA_B16(a, w1, ap4[1]);
      ap4[2] = MFMA_B16(a, w2, ap4[2]);
      ap4[3] = MFMA_B16(a, w3, ap4[3]);
    }

    // ---- sample + write h
    #pragma unroll
    for (int nt = 0; nt < 2; ++nt)
      #pragma unroll
      for (int j = 0; j < 4; ++j){
        float mean = fminf(fmaxf(ap4[nt][j], -1000.f), 1000.f);
        float lvv  = fminf(fmaxf(ap4[2+nt][j], -30.f), 30.f);
        float s = mean + __expf(0.5f*lvv)*epsv[nt][j];
        hreg[nt][j] = s;
        int row = lg*4 + j, c = c0 + 16*nt + lr;
        *reinterpret_cast<ushort_t*>(smem + 131072 + row*512 + (((c>>3) ^ (row&7)) << 4) + (c&7)*2) = f2bf(s);
        size_t oi = (size_t)(b0+row)*262144 + (size_t)t*256 + c;
        size_t o2 = 16777216u + (size_t)(b0+row)*256 + c;
        if (b16){
          o16[oi] = f2bf(s);
          if (t == 1023) o16[o2] = f2bf(s);
        } else {
          o32[oi] = s;
          if (t == 1023) o32[o2] = s;
        }
      }
    __syncthreads();
  }
}

// ---------------------------------------------------------------- host
extern "C" void kernel_launch(void* const* d_in, const int* in_sizes, int n_in,
                              void* d_out, int out_size, void* d_ws, size_t ws_size,
                              hipStream_t stream)
{
  const void* x   = d_in[0];
  const void* h0  = d_in[1];
  const void* eps = d_in[2];
  const void* Wz  = d_in[3];
  const void* bz  = d_in[4];
  const void* Wr  = d_in[5];
  const void* br  = d_in[6];
  const void* Wtx = d_in[7];
  const void* btx = d_in[8];
  const void* Wth = d_in[9];
  const void* bth = d_in[10];
  const void* Wd  = d_in[11];
  const void* bd  = d_in[12];
  ushort_t* ws16 = (ushort_t*)d_ws;
  uint_t* flag = (uint_t*)((char*)d_ws + FLAG_BYTE);
  const ushort_t* aux = ws16 + AUX_OFF;

  detect_kernel<<<dim3(1), dim3(64), 0, stream>>>((const uint_t*)x, flag);
  prep_kernel<<<dim3(2118), dim3(256), 0, stream>>>(Wz, Wr, Wtx, Wth, Wd,
                                                    bz, br, btx, bth, bd, h0,
                                                    flag, ws16);

  const size_t need_f32 = (size_t)AX_OFF_BYTES + (size_t)65536 * 768 * 4;
  const int SMEM_REC = 147456;

  if (ws_size >= need_f32){
    float* Ax = (float*)((char*)d_ws + AX_OFF_BYTES);
    xproj_kernel<float><<<dim3(3072), dim3(256), 0, stream>>>(x, ws16, aux, flag, Ax);
    hipFuncSetAttribute(reinterpret_cast<const void*>(&gru_kernel<float>),
                        hipFuncAttributeMaxDynamicSharedMemorySize, SMEM_REC);
    gru_kernel<float><<<dim3(4), dim3(512), SMEM_REC, stream>>>(ws16, Ax, eps, flag, d_out);
  } else {
    ushort_t* Ax = (ushort_t*)((char*)d_ws + AX_OFF_BYTES);
    xproj_kernel<ushort_t><<<dim3(3072), dim3(256), 0, stream>>>(x, ws16, aux, flag, Ax);
    hipFuncSetAttribute(reinterpret_cast<const void*>(&gru_kernel<ushort_t>),
                        hipFuncAttributeMaxDynamicSharedMemorySize, SMEM_REC);
    gru_kernel<ushort_t><<<dim3(4), dim3(512), SMEM_REC, stream>>>(ws16, Ax, eps, flag, d_out);
  }
}